// Round 12
// baseline (325.842 us; speedup 1.0000x reference)
//
#include <hip/hip_runtime.h>
#include <hip/hip_bf16.h>
#include <string.h>

#define BB 4
#define CPc 256
#define NN 2304   // 48*48

typedef __attribute__((ext_vector_type(8))) short bf16x8;
typedef __attribute__((ext_vector_type(4))) float f32x4;

__device__ __forceinline__ short f2b(float x) {
    __hip_bfloat16 h = __float2bfloat16(x);
    return *reinterpret_cast<short*>(&h);
}
__device__ __forceinline__ float b2f16(short v) {
    union { float f; unsigned u; } x;
    x.u = ((unsigned)(unsigned short)v) << 16;
    return x.f;
}

// ---------------- K0: convert weights fp32 -> bf16 ----------------
__global__ __launch_bounds__(256) void k_wcvt(
    const float* __restrict__ t_w, const float* __restrict__ z_w,
    const float* p0, const float* p1, const float* p2, const float* p3, const float* p4,
    const float* g0, const float* g1, const float* g2, const float* g3, const float* g4,
    short* __restrict__ TWb, short* __restrict__ ZWb,
    short* __restrict__ WPb, short* __restrict__ WGb) {
    int idx = blockIdx.x * 256 + threadIdx.x;
    if (idx < 16384) { TWb[idx] = f2b(t_w[idx]); return; }
    if (idx < 32768) { ZWb[idx - 16384] = f2b(z_w[idx - 16384]); return; }
    int k = idx - 32768;
    bool isP = k < 249856;
    if (!isP) k -= 249856;
    int i, off;
    if (k < 4096)        { i = 0; off = 0; }
    else if (k < 20480)  { i = 1; off = 4096; }
    else if (k < 53248)  { i = 2; off = 20480; }
    else if (k < 118784) { i = 3; off = 53248; }
    else                 { i = 4; off = 118784; }
    const float* s;
    if (isP) s = (i == 0) ? p0 : (i == 1) ? p1 : (i == 2) ? p2 : (i == 3) ? p3 : p4;
    else     s = (i == 0) ? g0 : (i == 1) ? g1 : (i == 2) ? g2 : (i == 3) ? g3 : g4;
    (isP ? WPb : WGb)[k] = f2b(s[k - off]);
}

// ---------------- K1: batched MFMA 1x1 convs, LDS-staged, SPLIT-K ----------------
__global__ __launch_bounds__(256) void k_conv(
    const float* __restrict__ persp,
    const float* r0, const float* r1, const float* r2, const float* r3, const float* r4,
    const short* __restrict__ TWb, const short* __restrict__ WPb, const short* __restrict__ WGb,
    short* __restrict__ TQb, short* __restrict__ PTb, short* __restrict__ GTb,
    float* __restrict__ PPART, float* __restrict__ GPART) {
    const int CUM[7]  = {0, 144, 288, 432, 504, 552, 584};
    const int CRs[6]  = {256, 64, 256, 512, 1024, 2048};
    const int Mus[6]  = {2304, 2304, 2304, 576, 144, 36};
    const int Mps[6]  = {2304, 2304, 2304, 576, 192, 64};
    const int KSs[6]  = {1, 1, 1, 2, 4, 8};
    const int WOFF[6] = {0, 0, 4096, 20480, 53248, 118784};
    const int POFF[6] = {0, 0, 589824, 1179648, 1327104, 1376256};
    const int PBASE[6] = {0, 0, 0, 0, 294912, 491520};

    __shared__ __align__(16) short s_a[64][72];

    int blk = blockIdx.x, t = threadIdx.x;
    int w = t >> 6, lane = t & 63, lo = lane & 15, quad = lane >> 4;
    int seg = 0;
#pragma unroll
    for (int s_ = 1; s_ <= 5; ++s_) if (blk >= CUM[s_]) seg = s_;
    int Cr = CRs[seg], M = Mus[seg], Mp = Mps[seg], KS = KSs[seg];
    const float* in = (seg == 0) ? persp : (seg == 1) ? r0 : (seg == 2) ? r1 :
                      (seg == 3) ? r2 : (seg == 4) ? r3 : r4;
    const short* wp = (seg == 0) ? TWb : WPb + WOFF[seg];
    const short* wg = WGb + WOFF[seg];
    bool has_g = (seg != 0);
    int local = blk - CUM[seg];
    int mt = Mp >> 6;
    int b = local / (mt * KS);
    int rem = local % (mt * KS);
    int m0 = (rem / KS) * 64;
    int ksi = rem % KS;
    int kLen = Cr / KS, k0 = ksi * kLen;

    int ml = t & 63;
    int ssw = (ml >> 3) & 7;
    bool mvalid = (m0 + ml) < M;
    const float* inB = in + ((size_t)b * Cr) * M + m0 + ml;

    int mrow = w * 16 + lo;
    int rsw = (mrow >> 3) & 7;

    f32x4 accP[4], accG[4];
#pragma unroll
    for (int ct = 0; ct < 4; ++ct) {
        accP[ct] = f32x4{0.f, 0.f, 0.f, 0.f};
        accG[ct] = f32x4{0.f, 0.f, 0.f, 0.f};
    }

    for (int kc = k0; kc < k0 + kLen; kc += 64) {
        __syncthreads();
#pragma unroll
        for (int r = 0; r < 8; ++r) {
            int kp = (t >> 6) + r * 4;
            int q = kp >> 2, l = kp & 3;
            float v0 = 0.f, v1 = 0.f;
            if (mvalid) {
                v0 = inB[(size_t)(kc + 2 * kp) * M];
                v1 = inB[(size_t)(kc + 2 * kp + 1) * M];
            }
            short2 pk; pk.x = f2b(v0); pk.y = f2b(v1);
            *(short2*)&s_a[ml][(q ^ ssw) * 8 + l * 2] = pk;
        }
        __syncthreads();
        const bf16x8 fr0 = *(const bf16x8*)&s_a[mrow][8 * (quad ^ rsw)];
        const bf16x8 fr1 = *(const bf16x8*)&s_a[mrow][8 * ((4 + quad) ^ rsw)];
#pragma unroll
        for (int ct = 0; ct < 4; ++ct) {
            const bf16x8 fp0 = *(const bf16x8*)&wp[(size_t)(ct * 16 + lo) * Cr + kc + quad * 8];
            const bf16x8 fp1 = *(const bf16x8*)&wp[(size_t)(ct * 16 + lo) * Cr + kc + 32 + quad * 8];
            accP[ct] = __builtin_amdgcn_mfma_f32_16x16x32_bf16(fr0, fp0, accP[ct], 0, 0, 0);
            accP[ct] = __builtin_amdgcn_mfma_f32_16x16x32_bf16(fr1, fp1, accP[ct], 0, 0, 0);
            if (has_g) {
                const bf16x8 fg0 = *(const bf16x8*)&wg[(size_t)(ct * 16 + lo) * Cr + kc + quad * 8];
                const bf16x8 fg1 = *(const bf16x8*)&wg[(size_t)(ct * 16 + lo) * Cr + kc + 32 + quad * 8];
                accG[ct] = __builtin_amdgcn_mfma_f32_16x16x32_bf16(fg0, fr0, accG[ct], 0, 0, 0);
                accG[ct] = __builtin_amdgcn_mfma_f32_16x16x32_bf16(fg1, fr1, accG[ct], 0, 0, 0);
            }
        }
    }
    if (KS == 1) {
        short* outP = (seg == 0) ? TQb : PTb + POFF[seg];
        short* outG = GTb + POFF[seg];
        int mP = m0 + w * 16 + quad * 4;
#pragma unroll
        for (int ct = 0; ct < 4; ++ct) {
            int c = ct * 16 + lo;
#pragma unroll
            for (int rg = 0; rg < 4; ++rg)
                outP[((size_t)b * Mp + mP + rg) * 64 + c] = f2b(accP[ct][rg]);
        }
        if (has_g) {
            int mG = m0 + w * 16 + lo;
#pragma unroll
            for (int ct = 0; ct < 4; ++ct) {
                int cG = ct * 16 + quad * 4;
#pragma unroll
                for (int rg = 0; rg < 4; ++rg)
                    outG[((size_t)b * 64 + cG + rg) * Mp + mG] = f2b(accG[ct][rg]);
            }
        }
    } else {
        int NP = 4 * Mp * 64;
        float* pp = PPART + PBASE[seg] + (size_t)ksi * NP;
        float* gp = GPART + PBASE[seg] + (size_t)ksi * NP;
        int mP = m0 + w * 16 + quad * 4;
#pragma unroll
        for (int ct = 0; ct < 4; ++ct) {
            int c = ct * 16 + lo;
#pragma unroll
            for (int rg = 0; rg < 4; ++rg)
                pp[((size_t)b * Mp + mP + rg) * 64 + c] = accP[ct][rg];
        }
        int mG = m0 + w * 16 + lo;
#pragma unroll
        for (int ct = 0; ct < 4; ++ct) {
            int cG = ct * 16 + quad * 4;
#pragma unroll
            for (int rg = 0; rg < 4; ++rg)
                gp[((size_t)b * 64 + cG + rg) * Mp + mG] = accG[ct][rg];
        }
    }
}

// ---------------- K1b: reduce split-K partials -> bf16 PTb/GTb ----------------
__global__ __launch_bounds__(256) void k_cvt(const float* __restrict__ PPART,
                                             const float* __restrict__ GPART,
                                             short* __restrict__ PTb, short* __restrict__ GTb) {
    const int EC[4]    = {0, 147456, 196608, 212992};
    const int KSv[3]   = {2, 4, 8};
    const int PBASEv[3] = {0, 294912, 491520};
    const int POFFv[3] = {1179648, 1327104, 1376256};
    int e = blockIdx.x * 256 + threadIdx.x;
    int sg = (e < EC[1]) ? 0 : (e < EC[2]) ? 1 : 2;
    int rem = e - EC[sg];
    int KS = KSv[sg];
    int NP = (sg == 0) ? 147456 : (sg == 1) ? 49152 : 16384;
    {
        const float* src = PPART + PBASEv[sg] + rem;
        float p = 0.f;
        for (int s = 0; s < KS; ++s) p += src[(size_t)s * NP];
        PTb[POFFv[sg] + rem] = f2b(p);
    }
    {
        const float* src = GPART + PBASEv[sg] + rem;
        float g = 0.f;
        for (int s = 0; s < KS; ++s) g += src[(size_t)s * NP];
        GTb[POFFv[sg] + rem] = f2b(g);
    }
}

// ---------------- K2: MFMA attention, constant-shift softmax, batched loads ----
// All 16 global b128 loads (p + g) hoisted to chunk top -> one latency/chunk.
// Double-buffered wave-private s_P breaks the cross-chunk LDS WAR. Grid 1584.
__global__ __launch_bounds__(256) void k_attn(const short* __restrict__ tq,
                                              const short* __restrict__ PTb,
                                              const short* __restrict__ GTb,
                                              float* __restrict__ OUT,
                                              float* __restrict__ APART,
                                              float* __restrict__ AL) {
    const int AM[5]    = {2304, 2304, 576, 144, 36};
    const int AMp[5]   = {2304, 2304, 576, 192, 64};
    const int APOFF[5] = {0, 589824, 1179648, 1327104, 1376256};
    const int CUMA[6]  = {0, 576, 1152, 1296, 1440, 1584};

    __shared__ __align__(16) short s_P[2][4][16][72];   // double-buffered per-wave P'

    int t = threadIdx.x, blk = blockIdx.x;
    int seg = 0;
#pragma unroll
    for (int s_ = 1; s_ <= 4; ++s_) if (blk >= CUMA[s_]) seg = s_;
    int local = blk - CUMA[seg];
    int b, ntile, sl, nsl;
    if (seg < 2) { nsl = 4; b = local / 144; int r2 = local % 144; ntile = r2 >> 2; sl = r2 & 3; }
    else         { nsl = 1; b = local / 36; ntile = local % 36; sl = 0; }
    int n0 = ntile * 64;
    int M = AM[seg], Mp = AMp[seg];
    const short* pT = PTb + APOFF[seg];
    const short* gT = GTb + APOFF[seg];

    int w = t >> 6, lane = t & 63, lo = lane & 15, quad = lane >> 4;
    int nw = n0 + w * 16;
    bool domask = (M != Mp);   // only segs 3/4

    const short* tqB = tq + ((size_t)b * NN + nw + lo) * 64 + quad * 8;
    const bf16x8 bq0 = *(const bf16x8*)(tqB);
    const bf16x8 bq1 = *(const bf16x8*)(tqB + 32);

    const short* pBase = pT + ((size_t)b * Mp + lo) * 64 + quad * 8;
    const short* gBase = gT + ((size_t)b * 64 + lo) * Mp + quad * 8;

    f32x4 accO[4];
#pragma unroll
    for (int ct = 0; ct < 4; ++ct) accO[ct] = f32x4{0.f, 0.f, 0.f, 0.f};
    float lsum = 0.f;

    int nch = Mp >> 6;
    int cps = nch / nsl;
    int ch0 = sl * cps, ch1 = ch0 + cps;
    for (int ch = ch0; ch < ch1; ++ch) {
        int m0 = ch << 6;
        // ---- issue ALL loads for this chunk up front (16 x b128) ----
        bf16x8 pa[4][2], ga[4][2];
#pragma unroll
        for (int mt = 0; mt < 4; ++mt) {
            const short* pA = pBase + (size_t)(m0 + mt * 16) * 64;
            pa[mt][0] = *(const bf16x8*)(pA);
            pa[mt][1] = *(const bf16x8*)(pA + 32);
        }
#pragma unroll
        for (int ct = 0; ct < 4; ++ct) {
            const short* gB = gBase + (size_t)(ct * 16) * Mp + m0;
            ga[ct][0] = *(const bf16x8*)(gB);
            ga[ct][1] = *(const bf16x8*)(gB + 32);
        }
        // ---- QK ----
        f32x4 S[4];
#pragma unroll
        for (int mt = 0; mt < 4; ++mt) {
            S[mt] = f32x4{0.f, 0.f, 0.f, 0.f};
            S[mt] = __builtin_amdgcn_mfma_f32_16x16x32_bf16(pa[mt][0], bq0, S[mt], 0, 0, 0);
            S[mt] = __builtin_amdgcn_mfma_f32_16x16x32_bf16(pa[mt][1], bq1, S[mt], 0, 0, 0);
        }
        if (domask) {
#pragma unroll
            for (int mt = 0; mt < 4; ++mt)
#pragma unroll
                for (int rg = 0; rg < 4; ++rg)
                    if (m0 + mt * 16 + quad * 4 + rg >= M) S[mt][rg] = -1e30f;
        }
        // ---- exp with constant shift ----
        short (*sp)[72] = s_P[ch & 1][w];
#pragma unroll
        for (int mt = 0; mt < 4; ++mt) {
            short4 pw;
#pragma unroll
            for (int rg = 0; rg < 4; ++rg) {
                float e = __expf(S[mt][rg] - 40.f);
                lsum += e;
                ((short*)&pw)[rg] = f2b(e);
            }
            *(short4*)&sp[lo][mt * 16 + quad * 4] = pw;   // wave-local
        }
        // ---- AV ----
        const bf16x8 Pa0 = *(const bf16x8*)&sp[lo][quad * 8];
        const bf16x8 Pa1 = *(const bf16x8*)&sp[lo][32 + quad * 8];
#pragma unroll
        for (int ct = 0; ct < 4; ++ct) {
            accO[ct] = __builtin_amdgcn_mfma_f32_16x16x32_bf16(Pa0, ga[ct][0], accO[ct], 0, 0, 0);
            accO[ct] = __builtin_amdgcn_mfma_f32_16x16x32_bf16(Pa1, ga[ct][1], accO[ct], 0, 0, 0);
        }
    }
    lsum += __shfl_xor(lsum, 16, 64);
    lsum += __shfl_xor(lsum, 32, 64);
    if (nsl > 1) {
        int pi = seg * 4 + sl;
        float* op = APART + (size_t)pi * 589824;
#pragma unroll
        for (int ct = 0; ct < 4; ++ct)
#pragma unroll
            for (int rg = 0; rg < 4; ++rg) {
                int n = nw + quad * 4 + rg;
                op[((size_t)b * NN + n) * 64 + ct * 16 + lo] = accO[ct][rg];
            }
        if (quad == 0)
            AL[(size_t)pi * 9216 + (size_t)b * NN + nw + lo] = lsum;
    } else {
        float* outm = OUT + (size_t)seg * 589824;
        float linv[4];
#pragma unroll
        for (int rg = 0; rg < 4; ++rg)
            linv[rg] = 1.f / __shfl(lsum, quad * 4 + rg, 64);
#pragma unroll
        for (int ct = 0; ct < 4; ++ct)
#pragma unroll
            for (int rg = 0; rg < 4; ++rg) {
                int n = nw + quad * 4 + rg;
                outm[((size_t)b * NN + n) * 64 + ct * 16 + lo] = accO[ct][rg] * linv[rg];
            }
    }
}

// ---------------- K2b: merge 4 partials (segs 0/1), vectorized x4 ----------------
// grid = 2*589824/(256*4) = 1152
__global__ __launch_bounds__(256) void k_merge(const float* __restrict__ APART,
                                               const float* __restrict__ AL,
                                               float* __restrict__ OUT) {
    int e4 = (blockIdx.x * 256 + threadIdx.x) * 4;
    int seg = e4 / 589824;
    int rem = e4 % 589824;
    int row = rem >> 6;
    float L = 0.f;
    float4 O = {0.f, 0.f, 0.f, 0.f};
#pragma unroll
    for (int i = 0; i < 4; ++i) {
        L += AL[(size_t)(seg * 4 + i) * 9216 + row];
        float4 v = *(const float4*)&APART[(size_t)(seg * 4 + i) * 589824 + rem];
        O.x += v.x; O.y += v.y; O.z += v.z; O.w += v.w;
    }
    float li = 1.f / L;
    O.x *= li; O.y *= li; O.z *= li; O.w *= li;
    *(float4*)&OUT[(size_t)seg * 589824 + rem] = O;
}

// ---------------- K3: MFMA z-conv + fused BN stats ----------------
__global__ __launch_bounds__(256) void k_z(const float* __restrict__ OUT,
                                           const short* __restrict__ ZWb,
                                           short* __restrict__ Zb,
                                           float* __restrict__ STATS) {
    __shared__ __align__(16) short s_ut[64][72];
    int t = threadIdx.x;
    int seg = blockIdx.x / 144;
    int r = blockIdx.x % 144;
    int b = r / 36;
    int sp0 = (r % 36) * 64;
    const float* F = OUT + (size_t)seg * 589824 + (size_t)b * 147456;
    short* z = Zb + (size_t)seg * 2359296 + (size_t)b * 589824;
    float* stats = STATS + seg * 512;

    int w = t >> 6, lane = t & 63, lo = lane & 15, quad = lane >> 4;

    bf16x8 af[4][2];
#pragma unroll
    for (int qt = 0; qt < 4; ++qt)
#pragma unroll
        for (int h = 0; h < 2; ++h)
            af[qt][h] = *(const bf16x8*)&ZWb[(size_t)(w * 64 + qt * 16 + lo) * 64 + h * 32 + quad * 8];

#pragma unroll
    for (int rr = 0; rr < 4; ++rr) {
        int idx = t + rr * 256;
        int spl = idx & 63;
        int cp0 = (idx >> 6) << 2;
        short4 pk;
        pk.x = f2b(F[(size_t)(cp0 + 0) * 2304 + sp0 + spl]);
        pk.y = f2b(F[(size_t)(cp0 + 1) * 2304 + sp0 + spl]);
        pk.z = f2b(F[(size_t)(cp0 + 2) * 2304 + sp0 + spl]);
        pk.w = f2b(F[(size_t)(cp0 + 3) * 2304 + sp0 + spl]);
        *(short4*)&s_ut[spl][cp0] = pk;
    }
    __syncthreads();

    bf16x8 bfr[4][2];
#pragma unroll
    for (int st = 0; st < 4; ++st)
#pragma unroll
        for (int h = 0; h < 2; ++h)
            bfr[st][h] = *(const bf16x8*)&s_ut[st * 16 + lo][h * 32 + quad * 8];

    f32x4 acc[4][4];
#pragma unroll
    for (int qt = 0; qt < 4; ++qt)
#pragma unroll
        for (int st = 0; st < 4; ++st) {
            acc[qt][st] = f32x4{0.f, 0.f, 0.f, 0.f};
            acc[qt][st] = __builtin_amdgcn_mfma_f32_16x16x32_bf16(af[qt][0], bfr[st][0], acc[qt][st], 0, 0, 0);
            acc[qt][st] = __builtin_amdgcn_mfma_f32_16x16x32_bf16(af[qt][1], bfr[st][1], acc[qt][st], 0, 0, 0);
        }

#pragma unroll
    for (int qt = 0; qt < 4; ++qt) {
        float s1[4] = {0.f, 0.f, 0.f, 0.f};
        float s2[4] = {0.f, 0.f, 0.f, 0.f};
        int qb = w * 64 + qt * 16 + quad * 4;
#pragma unroll
        for (int st = 0; st < 4; ++st) {
            int sp = sp0 + st * 16 + lo;
#pragma unroll
            for (int rg = 0; rg < 4; ++rg) {
                float v = acc[qt][st][rg];
                z[(size_t)(qb + rg) * 2304 + sp] = f2b(v);
                s1[rg] += v;
                s2[rg] += v * v;
            }
        }
#pragma unroll
        for (int rg = 0; rg < 4; ++rg) {
            for (int o = 8; o >= 1; o >>= 1) {
                s1[rg] += __shfl_xor(s1[rg], o, 16);
                s2[rg] += __shfl_xor(s2[rg], o, 16);
            }
            if (lo == 0) {
                atomicAdd(&stats[(qb + rg) * 2], s1[rg]);
                atomicAdd(&stats[(qb + rg) * 2 + 1], s2[rg]);
            }
        }
    }
}

// ---------------- K4: final BN-normalize-and-sum, vectorized x4 ----------------
__global__ __launch_bounds__(256) void k_final(
    const short* __restrict__ Zb, const float* __restrict__ STATS,
    const float* g0, const float* g1, const float* g2, const float* g3, const float* g4,
    const float* b0, const float* b1, const float* b2, const float* b3, const float* b4,
    float* __restrict__ outp) {
    int idx4 = (blockIdx.x * 256 + threadIdx.x) * 4;
    int q = (idx4 / NN) & 255;
    const float inv = 1.f / (float)(BB * NN);
    float4 o = {0.f, 0.f, 0.f, 0.f};
#pragma unroll
    for (int i = 0; i < 5; ++i) {
        float mean = STATS[i * 512 + q * 2] * inv;
        float var = STATS[i * 512 + q * 2 + 1] * inv - mean * mean;
        float rr = rsqrtf(var + 1e-5f);
        const float* gm = (i == 0) ? g0 : (i == 1) ? g1 : (i == 2) ? g2 : (i == 3) ? g3 : g4;
        const float* bt = (i == 0) ? b0 : (i == 1) ? b1 : (i == 2) ? b2 : (i == 3) ? b3 : b4;
        float sc = rr * gm[q];
        float ofs = bt[q] - mean * sc;
        short4 zv = *(const short4*)&Zb[(size_t)i * 2359296 + idx4];
        o.x += b2f16(zv.x) * sc + ofs;
        o.y += b2f16(zv.y) * sc + ofs;
        o.z += b2f16(zv.z) * sc + ofs;
        o.w += b2f16(zv.w) * sc + ofs;
    }
    *(float4*)&outp[idx4] = o;
}

extern "C" void kernel_launch(void* const* d_in, const int* in_sizes, int n_in,
                              void* d_out, int out_size, void* d_ws, size_t ws_size,
                              hipStream_t stream) {
    const float* persp = (const float*)d_in[0];
    const float* resp[5];
    for (int i = 0; i < 5; ++i) resp[i] = (const float*)d_in[1 + i];
    const float* t_w = (const float*)d_in[6];
    const float* z_w = (const float*)d_in[7];
    const float *p_w[5], *g_w[5], *bng[5], *bnb[5];
    for (int i = 0; i < 5; ++i) {
        p_w[i] = (const float*)d_in[8 + 4 * i];
        g_w[i] = (const float*)d_in[9 + 4 * i];
        bng[i] = (const float*)d_in[10 + 4 * i];
        bnb[i] = (const float*)d_in[11 + 4 * i];
    }
    short* TQb = (short*)d_ws;              // 589824
    short* TWb = TQb + 589824;              // 16384
    short* ZWb = TWb + 16384;               // 16384
    short* WPb = ZWb + 16384;               // 249856
    short* WGb = WPb + 249856;              // 249856
    short* PTb = WGb + 249856;              // 1392640
    short* GTb = PTb + 1392640;             // 1392640
    short* Zb  = GTb + 1392640;             // 11796480 shorts
    float* OUT   = (float*)d_ws + 7852032;  // 2949120 floats
    float* STATS = OUT + 2949120;           // 2560
    float* PPART = STATS + 2560;            // 622592
    float* GPART = PPART + 622592;          // 622592
    float* APART = (float*)Zb;              // overlays Zb (dead until k_z)
    float* AL    = APART + 4718592;         // 73728 floats

    hipMemsetAsync(STATS, 0, 2560 * sizeof(float), stream);
    k_wcvt<<<2080, 256, 0, stream>>>(t_w, z_w,
        p_w[0], p_w[1], p_w[2], p_w[3], p_w[4],
        g_w[0], g_w[1], g_w[2], g_w[3], g_w[4],
        TWb, ZWb, WPb, WGb);
    k_conv<<<584, 256, 0, stream>>>(persp,
        resp[0], resp[1], resp[2], resp[3], resp[4],
        TWb, WPb, WGb, TQb, PTb, GTb, PPART, GPART);
    k_cvt<<<832, 256, 0, stream>>>(PPART, GPART, PTb, GTb);
    k_attn<<<1584, 256, 0, stream>>>(TQb, PTb, GTb, OUT, APART, AL);
    k_merge<<<1152, 256, 0, stream>>>(APART, AL, OUT);
    k_z<<<720, 256, 0, stream>>>(OUT, ZWb, Zb, STATS);
    k_final<<<2304, 256, 0, stream>>>(Zb, STATS,
        bng[0], bng[1], bng[2], bng[3], bng[4],
        bnb[0], bnb[1], bnb[2], bnb[3], bnb[4],
        (float*)d_out);
}

// Round 13
// 282.565 us; speedup vs baseline: 1.1532x; 1.1532x over previous
//
#include <hip/hip_runtime.h>
#include <hip/hip_bf16.h>
#include <string.h>

#define BB 4
#define CPc 256
#define NN 2304   // 48*48

typedef __attribute__((ext_vector_type(8))) short bf16x8;
typedef __attribute__((ext_vector_type(4))) float f32x4;

__device__ __forceinline__ short f2b(float x) {
    __hip_bfloat16 h = __float2bfloat16(x);
    return *reinterpret_cast<short*>(&h);
}
__device__ __forceinline__ float b2f16(short v) {
    union { float f; unsigned u; } x;
    x.u = ((unsigned)(unsigned short)v) << 16;
    return x.f;
}

// ---------------- K0: convert weights fp32 -> bf16 ----------------
__global__ __launch_bounds__(256) void k_wcvt(
    const float* __restrict__ t_w, const float* __restrict__ z_w,
    const float* p0, const float* p1, const float* p2, const float* p3, const float* p4,
    const float* g0, const float* g1, const float* g2, const float* g3, const float* g4,
    short* __restrict__ TWb, short* __restrict__ ZWb,
    short* __restrict__ WPb, short* __restrict__ WGb) {
    int idx = blockIdx.x * 256 + threadIdx.x;
    if (idx < 16384) { TWb[idx] = f2b(t_w[idx]); return; }
    if (idx < 32768) { ZWb[idx - 16384] = f2b(z_w[idx - 16384]); return; }
    int k = idx - 32768;
    bool isP = k < 249856;
    if (!isP) k -= 249856;
    int i, off;
    if (k < 4096)        { i = 0; off = 0; }
    else if (k < 20480)  { i = 1; off = 4096; }
    else if (k < 53248)  { i = 2; off = 20480; }
    else if (k < 118784) { i = 3; off = 53248; }
    else                 { i = 4; off = 118784; }
    const float* s;
    if (isP) s = (i == 0) ? p0 : (i == 1) ? p1 : (i == 2) ? p2 : (i == 3) ? p3 : p4;
    else     s = (i == 0) ? g0 : (i == 1) ? g1 : (i == 2) ? g2 : (i == 3) ? g3 : g4;
    (isP ? WPb : WGb)[k] = f2b(s[k - off]);
}

// ---------------- K1: batched MFMA 1x1 convs, LDS-staged, SPLIT-K ----------------
__global__ __launch_bounds__(256) void k_conv(
    const float* __restrict__ persp,
    const float* r0, const float* r1, const float* r2, const float* r3, const float* r4,
    const short* __restrict__ TWb, const short* __restrict__ WPb, const short* __restrict__ WGb,
    short* __restrict__ TQb, short* __restrict__ PTb, short* __restrict__ GTb,
    float* __restrict__ PPART, float* __restrict__ GPART) {
    const int CUM[7]  = {0, 144, 288, 432, 504, 552, 584};
    const int CRs[6]  = {256, 64, 256, 512, 1024, 2048};
    const int Mus[6]  = {2304, 2304, 2304, 576, 144, 36};
    const int Mps[6]  = {2304, 2304, 2304, 576, 192, 64};
    const int KSs[6]  = {1, 1, 1, 2, 4, 8};
    const int WOFF[6] = {0, 0, 4096, 20480, 53248, 118784};
    const int POFF[6] = {0, 0, 589824, 1179648, 1327104, 1376256};
    const int PBASE[6] = {0, 0, 0, 0, 294912, 491520};

    __shared__ __align__(16) short s_a[64][72];

    int blk = blockIdx.x, t = threadIdx.x;
    int w = t >> 6, lane = t & 63, lo = lane & 15, quad = lane >> 4;
    int seg = 0;
#pragma unroll
    for (int s_ = 1; s_ <= 5; ++s_) if (blk >= CUM[s_]) seg = s_;
    int Cr = CRs[seg], M = Mus[seg], Mp = Mps[seg], KS = KSs[seg];
    const float* in = (seg == 0) ? persp : (seg == 1) ? r0 : (seg == 2) ? r1 :
                      (seg == 3) ? r2 : (seg == 4) ? r3 : r4;
    const short* wp = (seg == 0) ? TWb : WPb + WOFF[seg];
    const short* wg = WGb + WOFF[seg];
    bool has_g = (seg != 0);
    int local = blk - CUM[seg];
    int mt = Mp >> 6;
    int b = local / (mt * KS);
    int rem = local % (mt * KS);
    int m0 = (rem / KS) * 64;
    int ksi = rem % KS;
    int kLen = Cr / KS, k0 = ksi * kLen;

    int ml = t & 63;
    int ssw = (ml >> 3) & 7;
    bool mvalid = (m0 + ml) < M;
    const float* inB = in + ((size_t)b * Cr) * M + m0 + ml;

    int mrow = w * 16 + lo;
    int rsw = (mrow >> 3) & 7;

    f32x4 accP[4], accG[4];
#pragma unroll
    for (int ct = 0; ct < 4; ++ct) {
        accP[ct] = f32x4{0.f, 0.f, 0.f, 0.f};
        accG[ct] = f32x4{0.f, 0.f, 0.f, 0.f};
    }

    for (int kc = k0; kc < k0 + kLen; kc += 64) {
        __syncthreads();
#pragma unroll
        for (int r = 0; r < 8; ++r) {
            int kp = (t >> 6) + r * 4;
            int q = kp >> 2, l = kp & 3;
            float v0 = 0.f, v1 = 0.f;
            if (mvalid) {
                v0 = inB[(size_t)(kc + 2 * kp) * M];
                v1 = inB[(size_t)(kc + 2 * kp + 1) * M];
            }
            short2 pk; pk.x = f2b(v0); pk.y = f2b(v1);
            *(short2*)&s_a[ml][(q ^ ssw) * 8 + l * 2] = pk;
        }
        __syncthreads();
        const bf16x8 fr0 = *(const bf16x8*)&s_a[mrow][8 * (quad ^ rsw)];
        const bf16x8 fr1 = *(const bf16x8*)&s_a[mrow][8 * ((4 + quad) ^ rsw)];
#pragma unroll
        for (int ct = 0; ct < 4; ++ct) {
            const bf16x8 fp0 = *(const bf16x8*)&wp[(size_t)(ct * 16 + lo) * Cr + kc + quad * 8];
            const bf16x8 fp1 = *(const bf16x8*)&wp[(size_t)(ct * 16 + lo) * Cr + kc + 32 + quad * 8];
            accP[ct] = __builtin_amdgcn_mfma_f32_16x16x32_bf16(fr0, fp0, accP[ct], 0, 0, 0);
            accP[ct] = __builtin_amdgcn_mfma_f32_16x16x32_bf16(fr1, fp1, accP[ct], 0, 0, 0);
            if (has_g) {
                const bf16x8 fg0 = *(const bf16x8*)&wg[(size_t)(ct * 16 + lo) * Cr + kc + quad * 8];
                const bf16x8 fg1 = *(const bf16x8*)&wg[(size_t)(ct * 16 + lo) * Cr + kc + 32 + quad * 8];
                accG[ct] = __builtin_amdgcn_mfma_f32_16x16x32_bf16(fg0, fr0, accG[ct], 0, 0, 0);
                accG[ct] = __builtin_amdgcn_mfma_f32_16x16x32_bf16(fg1, fr1, accG[ct], 0, 0, 0);
            }
        }
    }
    if (KS == 1) {
        short* outP = (seg == 0) ? TQb : PTb + POFF[seg];
        short* outG = GTb + POFF[seg];
        int mP = m0 + w * 16 + quad * 4;
#pragma unroll
        for (int ct = 0; ct < 4; ++ct) {
            int c = ct * 16 + lo;
#pragma unroll
            for (int rg = 0; rg < 4; ++rg)
                outP[((size_t)b * Mp + mP + rg) * 64 + c] = f2b(accP[ct][rg]);
        }
        if (has_g) {
            int mG = m0 + w * 16 + lo;
#pragma unroll
            for (int ct = 0; ct < 4; ++ct) {
                int cG = ct * 16 + quad * 4;
#pragma unroll
                for (int rg = 0; rg < 4; ++rg)
                    outG[((size_t)b * 64 + cG + rg) * Mp + mG] = f2b(accG[ct][rg]);
            }
        }
    } else {
        int NP = 4 * Mp * 64;
        float* pp = PPART + PBASE[seg] + (size_t)ksi * NP;
        float* gp = GPART + PBASE[seg] + (size_t)ksi * NP;
        int mP = m0 + w * 16 + quad * 4;
#pragma unroll
        for (int ct = 0; ct < 4; ++ct) {
            int c = ct * 16 + lo;
#pragma unroll
            for (int rg = 0; rg < 4; ++rg)
                pp[((size_t)b * Mp + mP + rg) * 64 + c] = accP[ct][rg];
        }
        int mG = m0 + w * 16 + lo;
#pragma unroll
        for (int ct = 0; ct < 4; ++ct) {
            int cG = ct * 16 + quad * 4;
#pragma unroll
            for (int rg = 0; rg < 4; ++rg)
                gp[((size_t)b * 64 + cG + rg) * Mp + mG] = accG[ct][rg];
        }
    }
}

// ---------------- K1b: reduce split-K partials -> bf16 PTb/GTb ----------------
__global__ __launch_bounds__(256) void k_cvt(const float* __restrict__ PPART,
                                             const float* __restrict__ GPART,
                                             short* __restrict__ PTb, short* __restrict__ GTb) {
    const int EC[4]    = {0, 147456, 196608, 212992};
    const int KSv[3]   = {2, 4, 8};
    const int PBASEv[3] = {0, 294912, 491520};
    const int POFFv[3] = {1179648, 1327104, 1376256};
    int e = blockIdx.x * 256 + threadIdx.x;
    int sg = (e < EC[1]) ? 0 : (e < EC[2]) ? 1 : 2;
    int rem = e - EC[sg];
    int KS = KSv[sg];
    int NP = (sg == 0) ? 147456 : (sg == 1) ? 49152 : 16384;
    {
        const float* src = PPART + PBASEv[sg] + rem;
        float p = 0.f;
        for (int s = 0; s < KS; ++s) p += src[(size_t)s * NP];
        PTb[POFFv[sg] + rem] = f2b(p);
    }
    {
        const float* src = GPART + PBASEv[sg] + rem;
        float g = 0.f;
        for (int s = 0; s < KS; ++s) g += src[(size_t)s * NP];
        GTb[POFFv[sg] + rem] = f2b(g);
    }
}

// ---------------- K2: MFMA attention — R8 dataflow + constant-shift softmax ----
// 32 q-rows/block; wave w owns m-tile w (QK) and c-tile w (AV): only 4 b128
// loads/chunk/wave, software-prefetched one chunk ahead (loop-carried regs the
// compiler cannot sink). exp(s-40) fixed shift: no cross-wave softmax state;
// P' via double-buffered LDS, ONE barrier/chunk; l reduced once at end.
// grid = 5 * 288 = 1440
__global__ __launch_bounds__(256) void k_attn(const short* __restrict__ tq,
                                              const short* __restrict__ PTb,
                                              const short* __restrict__ GTb,
                                              float* __restrict__ OUT) {
    const int AM[5]    = {2304, 2304, 576, 144, 36};
    const int AMp[5]   = {2304, 2304, 576, 192, 64};
    const int APOFF[5] = {0, 589824, 1179648, 1327104, 1376256};

    __shared__ __align__(16) short s_P[2][32][72];
    __shared__ float s_l[4][32];

    int t = threadIdx.x;
    int seg = blockIdx.x / 288;
    int r = blockIdx.x % 288;
    int b = r / 72;
    int n0 = (r % 72) * 32;
    int M = AM[seg], Mp = AMp[seg];
    const short* pT = PTb + APOFF[seg];
    const short* gT = GTb + APOFF[seg];
    float* outm = OUT + (size_t)seg * 589824;

    int w = t >> 6, lane = t & 63, lo = lane & 15, quad = lane >> 4;
    bool domask = (M != Mp);   // segs 3/4 only

    const short* tqB = tq + ((size_t)b * NN + n0 + lo) * 64 + quad * 8;
    bf16x8 bq[2][2];
#pragma unroll
    for (int i = 0; i < 2; ++i)
#pragma unroll
        for (int h = 0; h < 2; ++h)
            bq[i][h] = *(const bf16x8*)(tqB + i * 16 * 64 + h * 32);

    const short* pA = pT + ((size_t)b * Mp + w * 16 + lo) * 64 + quad * 8;
    const short* gB = gT + ((size_t)b * 64 + w * 16 + lo) * Mp + quad * 8;

    bf16x8 pa0 = *(const bf16x8*)(pA);
    bf16x8 pa1 = *(const bf16x8*)(pA + 32);
    bf16x8 gb0 = *(const bf16x8*)(gB);
    bf16x8 gb1 = *(const bf16x8*)(gB + 32);

    f32x4 accO[2];
    accO[0] = f32x4{0.f, 0.f, 0.f, 0.f};
    accO[1] = f32x4{0.f, 0.f, 0.f, 0.f};
    float lsum[2] = {0.f, 0.f};   // partial l for columns n=lo / 16+lo, this wave's m-tile

    int nch = Mp >> 6;
    for (int ch = 0; ch < nch; ++ch) {
        int m0 = ch << 6;
        // software prefetch next chunk (loop-carried: compiler must keep in flight)
        bf16x8 pa0n, pa1n, gb0n, gb1n;
        bool more = (ch + 1 < nch);
        if (more) {
            int mn = m0 + 64;
            pa0n = *(const bf16x8*)(pA + (size_t)mn * 64);
            pa1n = *(const bf16x8*)(pA + (size_t)mn * 64 + 32);
            gb0n = *(const bf16x8*)(gB + mn);
            gb1n = *(const bf16x8*)(gB + mn + 32);
        }
        // QK: wave's m-tile vs both n-tiles
        f32x4 S[2];
        S[0] = f32x4{0.f, 0.f, 0.f, 0.f};
        S[0] = __builtin_amdgcn_mfma_f32_16x16x32_bf16(pa0, bq[0][0], S[0], 0, 0, 0);
        S[0] = __builtin_amdgcn_mfma_f32_16x16x32_bf16(pa1, bq[0][1], S[0], 0, 0, 0);
        S[1] = f32x4{0.f, 0.f, 0.f, 0.f};
        S[1] = __builtin_amdgcn_mfma_f32_16x16x32_bf16(pa0, bq[1][0], S[1], 0, 0, 0);
        S[1] = __builtin_amdgcn_mfma_f32_16x16x32_bf16(pa1, bq[1][1], S[1], 0, 0, 0);
        if (domask) {
#pragma unroll
            for (int rg = 0; rg < 4; ++rg) {
                bool oob = (m0 + w * 16 + quad * 4 + rg) >= M;
                if (oob) { S[0][rg] = -1e30f; S[1][rg] = -1e30f; }
            }
        }
        // exp with constant shift; accumulate per-lane l; write P'
        short (*sp)[72] = s_P[ch & 1];
#pragma unroll
        for (int i = 0; i < 2; ++i) {
            short4 pw;
#pragma unroll
            for (int rg = 0; rg < 4; ++rg) {
                float e = __expf(S[i][rg] - 40.f);
                lsum[i] += e;
                ((short*)&pw)[rg] = f2b(e);
            }
            *(short4*)&sp[i * 16 + lo][w * 16 + quad * 4] = pw;
        }
        __syncthreads();   // all waves' P' visible; dbuf prevents WAR on next chunk
        // AV: wave's c-tile, both n-tiles
#pragma unroll
        for (int i = 0; i < 2; ++i) {
            const bf16x8 a0 = *(const bf16x8*)&sp[i * 16 + lo][quad * 8];
            const bf16x8 a1 = *(const bf16x8*)&sp[i * 16 + lo][32 + quad * 8];
            accO[i] = __builtin_amdgcn_mfma_f32_16x16x32_bf16(a0, gb0, accO[i], 0, 0, 0);
            accO[i] = __builtin_amdgcn_mfma_f32_16x16x32_bf16(a1, gb1, accO[i], 0, 0, 0);
        }
        if (more) { pa0 = pa0n; pa1 = pa1n; gb0 = gb0n; gb1 = gb1n; }
    }
    // l: reduce over quads (per wave), then over waves via LDS (once)
#pragma unroll
    for (int i = 0; i < 2; ++i) {
        lsum[i] += __shfl_xor(lsum[i], 16, 64);
        lsum[i] += __shfl_xor(lsum[i], 32, 64);
    }
    if (quad == 0) { s_l[w][lo] = lsum[0]; s_l[w][16 + lo] = lsum[1]; }
    __syncthreads();
#pragma unroll
    for (int i = 0; i < 2; ++i)
#pragma unroll
        for (int rg = 0; rg < 4; ++rg) {
            int n = i * 16 + quad * 4 + rg;
            float lt = s_l[0][n] + s_l[1][n] + s_l[2][n] + s_l[3][n];
            outm[((size_t)b * NN + n0 + n) * 64 + w * 16 + lo] = accO[i][rg] / lt;
        }
}

// ---------------- K3: MFMA z-conv + fused BN stats ----------------
__global__ __launch_bounds__(256) void k_z(const float* __restrict__ OUT,
                                           const short* __restrict__ ZWb,
                                           short* __restrict__ Zb,
                                           float* __restrict__ STATS) {
    __shared__ __align__(16) short s_ut[64][72];
    int t = threadIdx.x;
    int seg = blockIdx.x / 144;
    int r = blockIdx.x % 144;
    int b = r / 36;
    int sp0 = (r % 36) * 64;
    const float* F = OUT + (size_t)seg * 589824 + (size_t)b * 147456;
    short* z = Zb + (size_t)seg * 2359296 + (size_t)b * 589824;
    float* stats = STATS + seg * 512;

    int w = t >> 6, lane = t & 63, lo = lane & 15, quad = lane >> 4;

    bf16x8 af[4][2];
#pragma unroll
    for (int qt = 0; qt < 4; ++qt)
#pragma unroll
        for (int h = 0; h < 2; ++h)
            af[qt][h] = *(const bf16x8*)&ZWb[(size_t)(w * 64 + qt * 16 + lo) * 64 + h * 32 + quad * 8];

#pragma unroll
    for (int rr = 0; rr < 4; ++rr) {
        int idx = t + rr * 256;
        int spl = idx & 63;
        int cp0 = (idx >> 6) << 2;
        short4 pk;
        pk.x = f2b(F[(size_t)(cp0 + 0) * 2304 + sp0 + spl]);
        pk.y = f2b(F[(size_t)(cp0 + 1) * 2304 + sp0 + spl]);
        pk.z = f2b(F[(size_t)(cp0 + 2) * 2304 + sp0 + spl]);
        pk.w = f2b(F[(size_t)(cp0 + 3) * 2304 + sp0 + spl]);
        *(short4*)&s_ut[spl][cp0] = pk;
    }
    __syncthreads();

    bf16x8 bfr[4][2];
#pragma unroll
    for (int st = 0; st < 4; ++st)
#pragma unroll
        for (int h = 0; h < 2; ++h)
            bfr[st][h] = *(const bf16x8*)&s_ut[st * 16 + lo][h * 32 + quad * 8];

    f32x4 acc[4][4];
#pragma unroll
    for (int qt = 0; qt < 4; ++qt)
#pragma unroll
        for (int st = 0; st < 4; ++st) {
            acc[qt][st] = f32x4{0.f, 0.f, 0.f, 0.f};
            acc[qt][st] = __builtin_amdgcn_mfma_f32_16x16x32_bf16(af[qt][0], bfr[st][0], acc[qt][st], 0, 0, 0);
            acc[qt][st] = __builtin_amdgcn_mfma_f32_16x16x32_bf16(af[qt][1], bfr[st][1], acc[qt][st], 0, 0, 0);
        }

#pragma unroll
    for (int qt = 0; qt < 4; ++qt) {
        float s1[4] = {0.f, 0.f, 0.f, 0.f};
        float s2[4] = {0.f, 0.f, 0.f, 0.f};
        int qb = w * 64 + qt * 16 + quad * 4;
#pragma unroll
        for (int st = 0; st < 4; ++st) {
            int sp = sp0 + st * 16 + lo;
#pragma unroll
            for (int rg = 0; rg < 4; ++rg) {
                float v = acc[qt][st][rg];
                z[(size_t)(qb + rg) * 2304 + sp] = f2b(v);
                s1[rg] += v;
                s2[rg] += v * v;
            }
        }
#pragma unroll
        for (int rg = 0; rg < 4; ++rg) {
            for (int o = 8; o >= 1; o >>= 1) {
                s1[rg] += __shfl_xor(s1[rg], o, 16);
                s2[rg] += __shfl_xor(s2[rg], o, 16);
            }
            if (lo == 0) {
                atomicAdd(&stats[(qb + rg) * 2], s1[rg]);
                atomicAdd(&stats[(qb + rg) * 2 + 1], s2[rg]);
            }
        }
    }
}

// ---------------- K4: final BN-normalize-and-sum, vectorized x4 ----------------
__global__ __launch_bounds__(256) void k_final(
    const short* __restrict__ Zb, const float* __restrict__ STATS,
    const float* g0, const float* g1, const float* g2, const float* g3, const float* g4,
    const float* b0, const float* b1, const float* b2, const float* b3, const float* b4,
    float* __restrict__ outp) {
    int idx4 = (blockIdx.x * 256 + threadIdx.x) * 4;
    int q = (idx4 / NN) & 255;
    const float inv = 1.f / (float)(BB * NN);
    float4 o = {0.f, 0.f, 0.f, 0.f};
#pragma unroll
    for (int i = 0; i < 5; ++i) {
        float mean = STATS[i * 512 + q * 2] * inv;
        float var = STATS[i * 512 + q * 2 + 1] * inv - mean * mean;
        float rr = rsqrtf(var + 1e-5f);
        const float* gm = (i == 0) ? g0 : (i == 1) ? g1 : (i == 2) ? g2 : (i == 3) ? g3 : g4;
        const float* bt = (i == 0) ? b0 : (i == 1) ? b1 : (i == 2) ? b2 : (i == 3) ? b3 : b4;
        float sc = rr * gm[q];
        float ofs = bt[q] - mean * sc;
        short4 zv = *(const short4*)&Zb[(size_t)i * 2359296 + idx4];
        o.x += b2f16(zv.x) * sc + ofs;
        o.y += b2f16(zv.y) * sc + ofs;
        o.z += b2f16(zv.z) * sc + ofs;
        o.w += b2f16(zv.w) * sc + ofs;
    }
    *(float4*)&outp[idx4] = o;
}

extern "C" void kernel_launch(void* const* d_in, const int* in_sizes, int n_in,
                              void* d_out, int out_size, void* d_ws, size_t ws_size,
                              hipStream_t stream) {
    const float* persp = (const float*)d_in[0];
    const float* resp[5];
    for (int i = 0; i < 5; ++i) resp[i] = (const float*)d_in[1 + i];
    const float* t_w = (const float*)d_in[6];
    const float* z_w = (const float*)d_in[7];
    const float *p_w[5], *g_w[5], *bng[5], *bnb[5];
    for (int i = 0; i < 5; ++i) {
        p_w[i] = (const float*)d_in[8 + 4 * i];
        g_w[i] = (const float*)d_in[9 + 4 * i];
        bng[i] = (const float*)d_in[10 + 4 * i];
        bnb[i] = (const float*)d_in[11 + 4 * i];
    }
    short* TQb = (short*)d_ws;              // 589824
    short* TWb = TQb + 589824;              // 16384
    short* ZWb = TWb + 16384;               // 16384
    short* WPb = ZWb + 16384;               // 249856
    short* WGb = WPb + 249856;              // 249856
    short* PTb = WGb + 249856;              // 1392640
    short* GTb = PTb + 1392640;             // 1392640
    short* Zb  = GTb + 1392640;             // 11796480 shorts
    float* OUT   = (float*)d_ws + 7852032;  // 2949120 floats
    float* STATS = OUT + 2949120;           // 2560
    float* PPART = STATS + 2560;            // 622592
    float* GPART = PPART + 622592;          // 622592

    hipMemsetAsync(STATS, 0, 2560 * sizeof(float), stream);
    k_wcvt<<<2080, 256, 0, stream>>>(t_w, z_w,
        p_w[0], p_w[1], p_w[2], p_w[3], p_w[4],
        g_w[0], g_w[1], g_w[2], g_w[3], g_w[4],
        TWb, ZWb, WPb, WGb);
    k_conv<<<584, 256, 0, stream>>>(persp,
        resp[0], resp[1], resp[2], resp[3], resp[4],
        TWb, WPb, WGb, TQb, PTb, GTb, PPART, GPART);
    k_cvt<<<832, 256, 0, stream>>>(PPART, GPART, PTb, GTb);
    k_attn<<<1440, 256, 0, stream>>>(TQb, PTb, GTb, OUT);
    k_z<<<720, 256, 0, stream>>>(OUT, ZWb, Zb, STATS);
    k_final<<<2304, 256, 0, stream>>>(Zb, STATS,
        bng[0], bng[1], bng[2], bng[3], bng[4],
        bnb[0], bnb[1], bnb[2], bnb[3], bnb[4],
        (float*)d_out);
}